// Round 6
// baseline (1043.619 us; speedup 1.0000x reference)
//
#include <hip/hip_runtime.h>

// VQ nearest-codebook: N=262144 rows x D=64, K=1024 codes.
// Numerics contract (bit-exact vs np f32 reference, verified in prior session):
//   dist_k = fl32( fl32(zsq - 2*dot_k) + cbsq_k ), argmin -> lowest index wins.
//   dot_k MUST be one sequential fmaf chain d=0..63 per row. DO NOT re-associate.
//   zsq/cbsq: f64-accumulate then round once. (2*s is exact; fp-contract of
//   zsq-2*s to fma(-2,s,zsq) is value-identical.)
//
// R9 change: per-wave rotated codebook walk (stagger) on top of R7 structure.
//   Rationale: R8 (R=1 @ cap-128) spilled (VGPR 40, WRITE 280MB) -> reverted
//   to R7 (520us, R=2, SMEM ping-pong). R7's residual 668 cyc/row stall is a
//   CONVOY: all 8 waves/CU run lockstep, every lgkmcnt(0) waits on the SAME
//   line -> memory-return re-syncs them; all miss sK$ together and stall
//   together (SIMD idle). Fix: wave w starts at row off(w) = 8*(wid +
//   4*bit8(blockIdx)) and wraps mod K. Stalls de-align (other wave covers),
//   misses become distinct+concurrent (MLP), trailers hit sK$ lines the
//   front-runner fetched 8-56 rows ago (<=14KB < 16KB sK$).
//   Rotated visit order => explicit tie-break (dist<best)||(dist==best&&k<bk)
//   to preserve lowest-index-wins on exact float ties (~+4% VALU).
//   NO per-thread arrays anywhere (scratch hazard) -- all named values.

#define VQ_D 64
#define VQ_MAXK 1024

typedef __attribute__((ext_vector_type(4))) float f4;
typedef const __attribute__((address_space(4))) f4* cb4c_t;
typedef const __attribute__((address_space(4))) float* fc_t;

// Two-row sequential fused-FMA chain step over one float4-worth of c
// (ascending d within each row's chain; chains independent -> ILP without
// reassociation). c is an SGPR-resident f4.
#define VQ_CH2(qa, qb, c) do { \
    s0 = fmaf((qa).x, (c).x, s0); s1 = fmaf((qb).x, (c).x, s1); \
    s0 = fmaf((qa).y, (c).y, s0); s1 = fmaf((qb).y, (c).y, s1); \
    s0 = fmaf((qa).z, (c).z, s0); s1 = fmaf((qb).z, (c).z, s1); \
    s0 = fmaf((qa).w, (c).w, s0); s1 = fmaf((qb).w, (c).w, s1); } while (0)

// f64 sum-of-squares over one float4 (order-free: tie-invariant).
#define VQ_SQ(acc, q) do { \
    (acc) += (double)(q).x * (double)(q).x; \
    (acc) += (double)(q).y * (double)(q).y; \
    (acc) += (double)(q).z * (double)(q).z; \
    (acc) += (double)(q).w * (double)(q).w; } while (0)

#define SBAR() __builtin_amdgcn_sched_barrier(0)

// kernel1: cbsq[k] = fl32(sum_d f64(cb[k][d]^2)). Same numerics as the old
// in-block prologue (f64 accumulate, round once).
__global__ void vq_cbsq_kernel(const float* __restrict__ cb,
                               float* __restrict__ cbsq, int K)
{
    const int k = blockIdx.x * blockDim.x + threadIdx.x;
    if (k >= K) return;
    const float* c = cb + (size_t)k * VQ_D;
    double s = 0.0;
    #pragma unroll
    for (int d = 0; d < VQ_D; ++d) { double v = (double)c[d]; s += v * v; }
    cbsq[k] = (float)s;
}

template <bool USE_WS>
__global__ __launch_bounds__(256, 2) void vq_argmin_kernel(
    const float* __restrict__ z_e,
    const float* __restrict__ cb,
    const float* __restrict__ cbsq_ws,   // valid iff USE_WS
    float* __restrict__ out,             // [N*D] z_q, then [N] indices (as float)
    int N, int K)
{
    __shared__ float s_cbsq[VQ_MAXK];    // used only if !USE_WS

    if (!USE_WS) {
        for (int k = threadIdx.x; k < K; k += blockDim.x) {
            const float* c = cb + (size_t)k * VQ_D;
            double s = 0.0;
            #pragma unroll
            for (int d = 0; d < VQ_D; ++d) { double v = (double)c[d]; s += v * v; }
            s_cbsq[k] = (float)s;
        }
        __syncthreads();
    }

    // Two rows per thread: n0 = b*512 + t, n1 = n0 + 256.
    int n0 = blockIdx.x * (2 * (int)blockDim.x) + threadIdx.x;
    if (n0 >= N) return;                 // after the (optional) barrier: legal
    int n1 = n0 + (int)blockDim.x;
    if (n1 >= N) n1 = n0;                // harmless duplicate; never hit here

    // Both z rows in 32 NAMED float4 registers (NOT arrays — scratch hazard).
    const float4* zp0 = (const float4*)(z_e + (size_t)n0 * VQ_D);
    const float4* zp1 = (const float4*)(z_e + (size_t)n1 * VQ_D);
    float4 a0  = zp0[0],  a1  = zp0[1],  a2  = zp0[2],  a3  = zp0[3];
    float4 a4  = zp0[4],  a5  = zp0[5],  a6  = zp0[6],  a7  = zp0[7];
    float4 a8  = zp0[8],  a9  = zp0[9],  a10 = zp0[10], a11 = zp0[11];
    float4 a12 = zp0[12], a13 = zp0[13], a14 = zp0[14], a15 = zp0[15];
    float4 b0  = zp1[0],  b1  = zp1[1],  b2  = zp1[2],  b3  = zp1[3];
    float4 b4  = zp1[4],  b5  = zp1[5],  b6  = zp1[6],  b7  = zp1[7];
    float4 b8  = zp1[8],  b9  = zp1[9],  b10 = zp1[10], b11 = zp1[11];
    float4 b12 = zp1[12], b13 = zp1[13], b14 = zp1[14], b15 = zp1[15];

    // ||z||^2 in f64, rounded once (per row).
    double zs0 = 0.0, zs1 = 0.0;
    VQ_SQ(zs0, a0);  VQ_SQ(zs0, a1);  VQ_SQ(zs0, a2);  VQ_SQ(zs0, a3);
    VQ_SQ(zs0, a4);  VQ_SQ(zs0, a5);  VQ_SQ(zs0, a6);  VQ_SQ(zs0, a7);
    VQ_SQ(zs0, a8);  VQ_SQ(zs0, a9);  VQ_SQ(zs0, a10); VQ_SQ(zs0, a11);
    VQ_SQ(zs0, a12); VQ_SQ(zs0, a13); VQ_SQ(zs0, a14); VQ_SQ(zs0, a15);
    VQ_SQ(zs1, b0);  VQ_SQ(zs1, b1);  VQ_SQ(zs1, b2);  VQ_SQ(zs1, b3);
    VQ_SQ(zs1, b4);  VQ_SQ(zs1, b5);  VQ_SQ(zs1, b6);  VQ_SQ(zs1, b7);
    VQ_SQ(zs1, b8);  VQ_SQ(zs1, b9);  VQ_SQ(zs1, b10); VQ_SQ(zs1, b11);
    VQ_SQ(zs1, b12); VQ_SQ(zs1, b13); VQ_SQ(zs1, b14); VQ_SQ(zs1, b15);
    const float zsq0 = (float)zs0;
    const float zsq1 = (float)zs1;

    // Constant-AS views -> uniform loads become s_load (SGPR-resident rows).
    cb4c_t cbc = (cb4c_t)(unsigned long long)cb;      // 16 f4 per row
    fc_t   sqc = (fc_t)(unsigned long long)cbsq_ws;

    // Per-wave rotation offset: 8 rows x (wid + 4*bit8(block)). Co-resident
    // blocks differ by 256 (512 blocks / 256 CUs) -> bit 8 separates them;
    // wid separates the 4 waves of a block. Offsets 0..56 rows, all distinct
    // per CU under the expected dispatch; worst case still 4-way stagger.
    const int wid = (int)(threadIdx.x >> 6);
    const int off = ((((int)(blockIdx.x >> 8) & 1) << 2) | wid) << 3;

    float best0 = 3.4e38f, best1 = 3.4e38f;
    int bk0 = 0x7fffffff, bk1 = 0x7fffffff;

    // Half-row ping-pong buffers (SGPR f4s). X = d0..31, Y = d32..63.
    f4 X0, X1, X2, X3, X4, X5, X6, X7;
    f4 Y0, Y1, Y2, Y3, Y4, Y5, Y6, Y7;
    float cq;

    // Prologue: issue A(off) into X. (One-time short-distance wait at k0=0.)
    {
        const int kb = off << 4;
        X0 = cbc[kb + 0]; X1 = cbc[kb + 1]; X2 = cbc[kb + 2]; X3 = cbc[kb + 3];
        X4 = cbc[kb + 4]; X5 = cbc[kb + 5]; X6 = cbc[kb + 6]; X7 = cbc[kb + 7];
    }

    #pragma unroll 1
    for (int k0 = 0; k0 < K; ++k0) {
        int k = k0 + off; if (k >= K) k -= K;      // rotated physical row
        const int kb = k << 4;
        float s0 = 0.f, s1 = 0.f;

        // First X use: lgkmcnt(0) lands HERE, draining X issued mid-B-block
        // of the previous iteration.
        VQ_CH2(a0, b0, X0);
        SBAR();
        // Issue box: B(k) -> Y, plus cbsq(k). Boxed so the scheduler can
        // neither hoist these above the X-wait nor sink them toward their use.
        Y0 = cbc[kb + 8];  Y1 = cbc[kb + 9];  Y2 = cbc[kb + 10]; Y3 = cbc[kb + 11];
        Y4 = cbc[kb + 12]; Y5 = cbc[kb + 13]; Y6 = cbc[kb + 14]; Y7 = cbc[kb + 15];
        cq = USE_WS ? sqc[k] : s_cbsq[k];
        SBAR();
        // Rest of A-half (d4..31), sequential ascending d.
        VQ_CH2(a1, b1, X1); VQ_CH2(a2, b2, X2); VQ_CH2(a3, b3, X3);
        VQ_CH2(a4, b4, X4); VQ_CH2(a5, b5, X5); VQ_CH2(a6, b6, X6);
        VQ_CH2(a7, b7, X7);

        // First Y use: lgkmcnt(0) lands HERE, draining Y+cq.
        VQ_CH2(a8, b8, Y0);
        SBAR();
        // Issue box: A(next) -> X (wraps mod K; last iter refetches the start
        // row — unused, harmless, never OOB).
        {
            int nk = k + 1; if (nk >= K) nk = 0;
            const int nb = nk << 4;
            X0 = cbc[nb + 0]; X1 = cbc[nb + 1]; X2 = cbc[nb + 2]; X3 = cbc[nb + 3];
            X4 = cbc[nb + 4]; X5 = cbc[nb + 5]; X6 = cbc[nb + 6]; X7 = cbc[nb + 7];
        }
        SBAR();
        // Rest of B-half (d36..63), sequential ascending d.
        VQ_CH2(a9,  b9,  Y1); VQ_CH2(a10, b10, Y2); VQ_CH2(a11, b11, Y3);
        VQ_CH2(a12, b12, Y4); VQ_CH2(a13, b13, Y5); VQ_CH2(a14, b14, Y6);
        VQ_CH2(a15, b15, Y7);

        // cq completed at the Y-wait; no further lgkm wait needed here.
        const float u0    = zsq0 - 2.0f * s0;   // 2*s exact; one fp32 round
        const float dist0 = u0 + cq;            // fp32 round, as reference
        const float u1    = zsq1 - 2.0f * s1;
        const float dist1 = u1 + cq;
        // Rotated visit order -> explicit lowest-index tie-break (exact ==).
        if (dist0 < best0 || (dist0 == best0 && k < bk0)) { best0 = dist0; bk0 = k; }
        if (dist1 < best1 || (dist1 == best1 && k < bk1)) { best1 = dist1; bk1 = k; }
    }

    // z_q gathers (divergent index -> per-lane VMEM; codebook L2-resident).
    {
        const float4* cq0 = (const float4*)(cb + (size_t)bk0 * VQ_D);
        float4* oq0 = (float4*)(out + (size_t)n0 * VQ_D);
        #pragma unroll
        for (int i = 0; i < VQ_D / 4; ++i) oq0[i] = cq0[i];
        const float4* cq1 = (const float4*)(cb + (size_t)bk1 * VQ_D);
        float4* oq1 = (float4*)(out + (size_t)n1 * VQ_D);
        #pragma unroll
        for (int i = 0; i < VQ_D / 4; ++i) oq1[i] = cq1[i];
    }

    // Indices as float (exact for k < 2^24).
    out[(size_t)N * VQ_D + n0] = (float)bk0;
    out[(size_t)N * VQ_D + n1] = (float)bk1;
}

extern "C" void kernel_launch(void* const* d_in, const int* in_sizes, int n_in,
                              void* d_out, int out_size, void* d_ws, size_t ws_size,
                              hipStream_t stream) {
    const float* z_e = (const float*)d_in[0];
    const float* cb  = (const float*)d_in[1];
    float* out = (float*)d_out;

    const int N = in_sizes[0] / VQ_D;
    const int K = in_sizes[1] / VQ_D;

    const int block = 256;
    const int rows_per_block = 2 * block;
    const int grid = (N + rows_per_block - 1) / rows_per_block;

    const bool use_ws = (d_ws != nullptr) && (ws_size >= (size_t)K * sizeof(float));
    if (use_ws) {
        float* cbsq = (float*)d_ws;
        vq_cbsq_kernel<<<(K + 255) / 256, 256, 0, stream>>>(cb, cbsq, K);
        vq_argmin_kernel<true><<<grid, block, 0, stream>>>(z_e, cb, cbsq, out, N, K);
    } else {
        vq_argmin_kernel<false><<<grid, block, 0, stream>>>(z_e, cb, nullptr, out, N, K);
    }
}